// Round 5
// baseline (557.978 us; speedup 1.0000x reference)
//
#include <hip/hip_runtime.h>
#include <hip/hip_bf16.h>

#define NN 50000
#define EE 800000

typedef __bf16 bf16x8 __attribute__((ext_vector_type(8)));
typedef float f32x4 __attribute__((ext_vector_type(4)));

__device__ inline float bf2f(unsigned int u) {
    union { unsigned int i; float f; } x; x.i = (u & 0xFFFFu) << 16; return x.f;
}
__device__ inline float bf2fh(unsigned int u) {
    union { unsigned int i; float f; } x; x.i = u & 0xFFFF0000u; return x.f;
}
__device__ inline void bf8_to_f(bf16x8 v, float* f) {
    const unsigned int* u = (const unsigned int*)&v;
    f[0] = bf2f(u[0]); f[1] = bf2fh(u[0]);
    f[2] = bf2f(u[1]); f[3] = bf2fh(u[1]);
    f[4] = bf2f(u[2]); f[5] = bf2fh(u[2]);
    f[6] = bf2f(u[3]); f[7] = bf2fh(u[3]);
}

// ---------------- zero deg/cursor/bins (graph-safe) ----------------
__global__ void k_zero(int* __restrict__ deg, int* __restrict__ curs, int* __restrict__ bins) {
    int i = blockIdx.x * 256 + threadIdx.x;
    if (i < NN) { deg[i] = 0; curs[i] = 0; }
    if (i < 128) bins[i] = 0;       // 64 hist bins + 64 cursors
}

// ---------------- CSR build ----------------
__global__ void k_deg(const int* __restrict__ et, int* __restrict__ deg) {
    int e = blockIdx.x * 256 + threadIdx.x;
    if (e < EE) atomicAdd(&deg[et[e * 3 + 2]], 1);
}

__global__ void k_scan1(const int* __restrict__ deg, int* __restrict__ incl, int* __restrict__ bsum) {
    __shared__ int s[1024];
    int i = blockIdx.x * 1024 + threadIdx.x;
    int v = (i < NN) ? deg[i] : 0;
    s[threadIdx.x] = v;
    __syncthreads();
    for (int off = 1; off < 1024; off <<= 1) {
        int t = (threadIdx.x >= off) ? s[threadIdx.x - off] : 0;
        __syncthreads();
        s[threadIdx.x] += t;
        __syncthreads();
    }
    if (i < NN) incl[i] = s[threadIdx.x];
    if (threadIdx.x == 1023) bsum[blockIdx.x] = s[1023];
}

__global__ void k_scan2(const int* __restrict__ bsum, int* __restrict__ boff) {
    if (threadIdx.x == 0 && blockIdx.x == 0) {
        int acc = 0;
        for (int i = 0; i < 49; ++i) { boff[i] = acc; acc += bsum[i]; }
    }
}

__global__ void k_scan3(const int* __restrict__ incl, const int* __restrict__ deg,
                        const int* __restrict__ boff, int* __restrict__ row_start) {
    int i = blockIdx.x * 1024 + threadIdx.x;
    if (i < NN) row_start[i] = incl[i] - deg[i] + boff[blockIdx.x];
}

__global__ void k_fill(const int* __restrict__ et, const int* __restrict__ row_start,
                       int* __restrict__ cursor, int* __restrict__ perm) {
    int e = blockIdx.x * 256 + threadIdx.x;
    if (e >= EE) return;
    int src = et[e * 3 + 0];
    int rel = et[e * 3 + 1];
    int dst = et[e * 3 + 2];
    int pos = row_start[dst] + atomicAdd(&cursor[dst], 1);
    perm[pos] = src | (rel << 16);      // src < 65536, rel < 16
}

// ---------------- degree counting-sort (descending): order[] ----------------
__global__ void k_hist(const int* __restrict__ deg, int* __restrict__ bins) {
    int i = blockIdx.x * 256 + threadIdx.x;
    if (i < NN) {
        int d = deg[i]; d = d > 63 ? 63 : d;
        atomicAdd(&bins[63 - d], 1);
    }
}
__global__ void k_binscan(const int* __restrict__ bins, int* __restrict__ binoff) {
    if (threadIdx.x == 0 && blockIdx.x == 0) {
        int acc = 0;
        for (int i = 0; i < 64; ++i) { binoff[i] = acc; acc += bins[i]; }
    }
}
__global__ void k_scatter(const int* __restrict__ deg, const int* __restrict__ binoff,
                          int* __restrict__ bincur, int* __restrict__ order) {
    int i = blockIdx.x * 256 + threadIdx.x;
    if (i < NN) {
        int d = deg[i]; d = d > 63 ? 63 : d;
        int key = 63 - d;
        int pos = binoff[key] + atomicAdd(&bincur[key], 1);
        order[pos] = i;
    }
}

// ---------------- fragment-major weight prep ----------------
__global__ void k_prep(const float* __restrict__ iw,
                       const float* __restrict__ basis0, const float* __restrict__ rootw0,
                       const float* __restrict__ basis1, const float* __restrict__ rootw1,
                       __bf16* __restrict__ WtInF, __bf16* __restrict__ WtF0, __bf16* __restrict__ WtF1) {
    int t = blockIdx.x * 256 + threadIdx.x;
    if (t < 2048) {
        int lane = t & 63, grp = t >> 6;       // grp = nblk*4+kk
        int kk = grp & 3, nblk = grp >> 2;
        int col = nblk * 16 + (lane & 15);
        int k0 = kk * 32 + (lane >> 4) * 8;
        bf16x8 v;
        #pragma unroll
        for (int j = 0; j < 8; ++j) v[j] = (__bf16)iw[(size_t)(k0 + j) * 128 + col];
        *(bf16x8*)(WtInF + (size_t)t * 8) = v;
        return;
    }
    t -= 2048;
    const float* basis = basis0; const float* rootw = rootw0; __bf16* W = WtF0;
    if (t >= 10240) { t -= 10240; basis = basis1; rootw = rootw1; W = WtF1; }
    if (t >= 10240) return;
    int lane = t & 63, grp = t >> 6;           // grp = nblk*20+kk
    int kk = grp % 20, nblk = grp / 20;
    int col = nblk * 16 + (lane & 15);
    int k0 = kk * 32 + (lane >> 4) * 8;
    bf16x8 v;
    #pragma unroll
    for (int j = 0; j < 8; ++j) {
        int k = k0 + j;
        float f = (k < 512) ? basis[(size_t)(k >> 7) * 16384 + (size_t)(k & 127) * 128 + col]
                            : rootw[(size_t)(k - 512) * 128 + col];
        v[j] = (__bf16)f;
    }
    *(bf16x8*)(W + (size_t)t * 8) = v;
}

// ---------------- input GEMM: x0 = nf(f32) @ input_w + b (bf16 out), 64-row tiles ----------------
__global__ void k_gemm_in(const float* __restrict__ A, const __bf16* __restrict__ WtInF,
                          const float* __restrict__ bias, __bf16* __restrict__ out, int M) {
    const int tid = threadIdx.x, wave = tid >> 6, lane = tid & 63;
    const int wr = wave >> 1, wc = wave & 1;
    const int l15 = lane & 15, lhi = lane >> 4;
    f32x4 acc[2][4] = {};
    #define LDAI(dst, KK) do { \
        _Pragma("unroll") \
        for (int m = 0; m < 2; ++m) { \
            int rw = blockIdx.x * 64 + wr * 32 + m * 16 + l15; \
            rw = rw < M ? rw : M - 1; \
            const float* ap = A + (size_t)rw * 128 + (KK) * 32 + lhi * 8; \
            float4 v0 = *(const float4*)ap, v1 = *(const float4*)(ap + 4); \
            bf16x8 f; \
            f[0]=(__bf16)v0.x; f[1]=(__bf16)v0.y; f[2]=(__bf16)v0.z; f[3]=(__bf16)v0.w; \
            f[4]=(__bf16)v1.x; f[5]=(__bf16)v1.y; f[6]=(__bf16)v1.z; f[7]=(__bf16)v1.w; \
            dst[m] = f; \
        } } while (0)
    #define LDBI(dst, KK) do { \
        _Pragma("unroll") \
        for (int n = 0; n < 4; ++n) \
            dst[n] = *(const bf16x8*)(WtInF + (((size_t)(wc * 4 + n) * 4 + (KK)) * 64 + lane) * 8); \
        } while (0)
    #define MMI(AA, BB) do { \
        _Pragma("unroll") for (int m = 0; m < 2; ++m) \
        _Pragma("unroll") for (int n = 0; n < 4; ++n) \
            acc[m][n] = __builtin_amdgcn_mfma_f32_16x16x32_bf16(AA[m], BB[n], acc[m][n], 0, 0, 0); \
        } while (0)
    bf16x8 aP[2], bP[4], aQ[2], bQ[4];
    LDAI(aP, 0); LDBI(bP, 0);
    #pragma unroll
    for (int tstep = 0; tstep < 2; ++tstep) {
        LDAI(aQ, 2 * tstep + 1); LDBI(bQ, 2 * tstep + 1);
        MMI(aP, bP);
        if (tstep < 1) { LDAI(aP, 2 * tstep + 2); LDBI(bP, 2 * tstep + 2); }
        MMI(aQ, bQ);
    }
    #pragma unroll
    for (int m = 0; m < 2; ++m)
        #pragma unroll
        for (int j = 0; j < 4; ++j) {
            int row = blockIdx.x * 64 + wr * 32 + m * 16 + lhi * 4 + j;
            if (row >= M) continue;
            #pragma unroll
            for (int n = 0; n < 4; ++n) {
                int col = wc * 64 + n * 16 + l15;
                out[(size_t)row * 128 + col] = (__bf16)(acc[m][n][j] + bias[col]);
            }
        }
}

// ---------------- gather + aggregate: degree-sorted, software-pipelined ----------------
// one wave per SORTED position; 16 lanes per edge (lane owns 8 channels);
// 8 edges per step, next step's loads prefetched during compute (4 loads in flight).
__global__ void k_agg5(const __bf16* __restrict__ x, const int* __restrict__ perm,
                       const int* __restrict__ rowst, const int* __restrict__ deg,
                       const float* __restrict__ att, const int* __restrict__ order,
                       __bf16* __restrict__ aggF, int nodeOff, int nodeCnt) {
    __shared__ float4 satt[16];
    if (threadIdx.x < 16) satt[threadIdx.x] = ((const float4*)att)[threadIdx.x];
    __syncthreads();
    int local = blockIdx.x * 4 + (threadIdx.x >> 6);
    if (local >= nodeCnt) return;
    int lane = threadIdx.x & 63;
    int e4 = lane >> 4, c8 = lane & 15;
    int node = order[nodeOff + local];
    int start = rowst[node], cnt = deg[node];
    float acc[4][8] = {};
    int nIt = (cnt + 7) >> 3;
    if (nIt > 0) {
        bf16x8 uA, uB; float4 cA, cB;
        {
            int eA = e4, eB = e4 + 4;
            bool vA = eA < cnt, vB = eB < cnt;
            int pA = vA ? perm[start + eA] : 0;
            int pB = vB ? perm[start + eB] : 0;
            uA = *(const bf16x8*)(x + (size_t)(pA & 0xFFFF) * 128 + c8 * 8);
            uB = *(const bf16x8*)(x + (size_t)(pB & 0xFFFF) * 128 + c8 * 8);
            cA = vA ? satt[pA >> 16] : make_float4(0.f, 0.f, 0.f, 0.f);
            cB = vB ? satt[pB >> 16] : make_float4(0.f, 0.f, 0.f, 0.f);
        }
        for (int s = 0; ; ++s) {
            bf16x8 nA, nB; float4 nCA, nCB;
            bool more = (s + 1 < nIt);
            if (more) {
                int eA = (s + 1) * 8 + e4, eB = eA + 4;
                bool vA = eA < cnt, vB = eB < cnt;
                int pA = vA ? perm[start + eA] : 0;
                int pB = vB ? perm[start + eB] : 0;
                nA = *(const bf16x8*)(x + (size_t)(pA & 0xFFFF) * 128 + c8 * 8);
                nB = *(const bf16x8*)(x + (size_t)(pB & 0xFFFF) * 128 + c8 * 8);
                nCA = vA ? satt[pA >> 16] : make_float4(0.f, 0.f, 0.f, 0.f);
                nCB = vB ? satt[pB >> 16] : make_float4(0.f, 0.f, 0.f, 0.f);
            }
            float fA[8], fB[8];
            bf8_to_f(uA, fA);
            bf8_to_f(uB, fB);
            #pragma unroll
            for (int j = 0; j < 8; ++j) {
                acc[0][j] += cA.x * fA[j]; acc[1][j] += cA.y * fA[j];
                acc[2][j] += cA.z * fA[j]; acc[3][j] += cA.w * fA[j];
            }
            #pragma unroll
            for (int j = 0; j < 8; ++j) {
                acc[0][j] += cB.x * fB[j]; acc[1][j] += cB.y * fB[j];
                acc[2][j] += cB.z * fB[j]; acc[3][j] += cB.w * fB[j];
            }
            if (!more) break;
            uA = nA; uB = nB; cA = nCA; cB = nCB;
        }
    }
    float dinv = (cnt > 0) ? 1.f / (float)cnt : 0.f;
    #pragma unroll
    for (int b = 0; b < 4; ++b)
        #pragma unroll
        for (int j = 0; j < 8; ++j) {
            float v = acc[b][j];
            v += __shfl_xor(v, 16);
            v += __shfl_xor(v, 32);
            acc[b][j] = v * dinv;
        }
    bf16x8 o;
    #pragma unroll
    for (int j = 0; j < 8; ++j) {
        float v = (e4 == 0) ? acc[0][j] : (e4 == 1) ? acc[1][j] : (e4 == 2) ? acc[2][j] : acc[3][j];
        o[j] = (__bf16)v;
    }
    size_t idx8 = (((size_t)(local >> 4) * 16 + e4 * 4 + (c8 >> 2)) * 64 + (c8 & 3) * 16 + (local & 15)) * 8;
    *(bf16x8*)(aggF + idx8) = o;
}

// ---------------- layer GEMM over sorted positions; LN(+ReLU) fused ----------------
template<int OUTF>
__global__ void k_gemm_layer(const __bf16* __restrict__ aggF, const __bf16* __restrict__ x,
                             const __bf16* __restrict__ WtF, const float* __restrict__ rb,
                             const float* __restrict__ g, const float* __restrict__ bb,
                             const int* __restrict__ order,
                             __bf16* __restrict__ outB, float* __restrict__ outF,
                             int rowOff, int nodeCnt) {
    __shared__ float red[2][2][64];
    __shared__ float murs[2][64];
    const int tid = threadIdx.x, wave = tid >> 6, lane = tid & 63;
    const int wr = wave >> 1, wc = wave & 1;
    const int l15 = lane & 15, lhi = lane >> 4;
    const int rowgrpBase = blockIdx.x * 4 + wr * 2;   // 16-node fragment groups
    int ordm[2];
    #pragma unroll
    for (int m = 0; m < 2; ++m) {
        int rw = blockIdx.x * 64 + wr * 32 + m * 16 + l15;
        rw = rw < nodeCnt ? rw : nodeCnt - 1;
        ordm[m] = order[rowOff + rw];
    }
    f32x4 acc[2][4] = {};
    #define LDA(dst, KK) do { \
        _Pragma("unroll") \
        for (int m = 0; m < 2; ++m) { \
            if ((KK) < 16) { \
                dst[m] = *(const bf16x8*)(aggF + (((size_t)(rowgrpBase + m) * 16 + (KK)) * 64 + lane) * 8); \
            } else { \
                dst[m] = *(const bf16x8*)(x + (size_t)ordm[m] * 128 + ((KK) - 16) * 32 + lhi * 8); \
            } \
        } } while (0)
    #define LDB(dst, KK) do { \
        _Pragma("unroll") \
        for (int n = 0; n < 4; ++n) \
            dst[n] = *(const bf16x8*)(WtF + (((size_t)(wc * 4 + n) * 20 + (KK)) * 64 + lane) * 8); \
        } while (0)
    #define MM(AA, BB) do { \
        _Pragma("unroll") for (int m = 0; m < 2; ++m) \
        _Pragma("unroll") for (int n = 0; n < 4; ++n) \
            acc[m][n] = __builtin_amdgcn_mfma_f32_16x16x32_bf16(AA[m], BB[n], acc[m][n], 0, 0, 0); \
        } while (0)
    bf16x8 aP[2], bP[4], aQ[2], bQ[4];
    LDA(aP, 0); LDB(bP, 0);
    #pragma unroll
    for (int t = 0; t < 10; ++t) {
        LDA(aQ, 2 * t + 1); LDB(bQ, 2 * t + 1);
        MM(aP, bP);
        if (t < 9) { LDA(aP, 2 * t + 2); LDB(bP, 2 * t + 2); }
        MM(aQ, bQ);
    }
    float colb[4];
    #pragma unroll
    for (int n = 0; n < 4; ++n) colb[n] = rb[wc * 64 + n * 16 + l15];
    #pragma unroll
    for (int m = 0; m < 2; ++m)
        #pragma unroll
        for (int j = 0; j < 4; ++j) {
            float s = 0.f, q = 0.f;
            #pragma unroll
            for (int n = 0; n < 4; ++n) {
                float v = acc[m][n][j] + colb[n];
                acc[m][n][j] = v;
                s += v; q += v * v;
            }
            #pragma unroll
            for (int o = 1; o < 16; o <<= 1) { s += __shfl_xor(s, o); q += __shfl_xor(q, o); }
            if (l15 == 0) {
                int r = wr * 32 + m * 16 + lhi * 4 + j;
                red[0][wc][r] = s; red[1][wc][r] = q;
            }
        }
    __syncthreads();
    if (tid < 64) {
        float s = red[0][0][tid] + red[0][1][tid];
        float q = red[1][0][tid] + red[1][1][tid];
        float mu = s * (1.f / 128.f);
        float var = q * (1.f / 128.f) - mu * mu;
        murs[0][tid] = mu;
        murs[1][tid] = rsqrtf(var + 1e-5f);
    }
    __syncthreads();
    float gg[4], gb[4];
    #pragma unroll
    for (int n = 0; n < 4; ++n) {
        int col = wc * 64 + n * 16 + l15;
        gg[n] = g[col]; gb[n] = bb[col];
    }
    #pragma unroll
    for (int m = 0; m < 2; ++m)
        #pragma unroll
        for (int j = 0; j < 4; ++j) {
            int rblk = wr * 32 + m * 16 + lhi * 4 + j;
            int lr = blockIdx.x * 64 + rblk;
            if (lr >= nodeCnt) continue;
            float mu = murs[0][rblk], rs = murs[1][rblk];
            int ord = order[rowOff + lr];
            size_t rowbase = (size_t)ord * 128;
            #pragma unroll
            for (int n = 0; n < 4; ++n) {
                int col = wc * 64 + n * 16 + l15;
                float v = (acc[m][n][j] - mu) * rs * gg[n] + gb[n];
                if (OUTF == 0) { v = fmaxf(v, 0.f); outB[rowbase + col] = (__bf16)v; }
                else           { outF[rowbase + col] = v; }
            }
        }
}

// ---------------- launch ----------------
extern "C" void kernel_launch(void* const* d_in, const int* in_sizes, int n_in,
                              void* d_out, int out_size, void* d_ws, size_t ws_size,
                              hipStream_t stream) {
    const float* nf      = (const float*)d_in[0];
    const int*   et      = (const int*)d_in[1];
    const float* input_w = (const float*)d_in[3];
    const float* input_b = (const float*)d_in[4];
    const float* basis0  = (const float*)d_in[5];
    const float* att0    = (const float*)d_in[6];
    const float* rootw0  = (const float*)d_in[7];
    const float* rootb0  = (const float*)d_in[8];
    const float* lng0    = (const float*)d_in[9];
    const float* lnb0    = (const float*)d_in[10];
    const float* basis1  = (const float*)d_in[11];
    const float* att1    = (const float*)d_in[12];
    const float* rootw1  = (const float*)d_in[13];
    const float* rootb1  = (const float*)d_in[14];
    const float* lng1    = (const float*)d_in[15];
    const float* lnb1    = (const float*)d_in[16];
    (void)in_sizes; (void)n_in; (void)out_size;

    char* ws = (char*)d_ws;
    size_t off = 0;
    auto carve = [&](size_t bytes) { char* p = ws + off; off = (off + bytes + 255) & ~(size_t)255; return p; };
    __bf16* x0    = (__bf16*)carve((size_t)NN * 128 * 2);     // 12.8 MB
    __bf16* x1    = (__bf16*)carve((size_t)NN * 128 * 2);     // 12.8 MB
    __bf16* WtInF = (__bf16*)carve((size_t)128 * 128 * 2);
    __bf16* WtF0  = (__bf16*)carve((size_t)128 * 640 * 2);
    __bf16* WtF1  = (__bf16*)carve((size_t)128 * 640 * 2);
    int*    deg   = (int*)carve((size_t)NN * 4);
    int*    incl  = (int*)carve((size_t)NN * 4);
    int*    rowst = (int*)carve((size_t)NN * 4);
    int*    curs  = (int*)carve((size_t)NN * 4);
    int*    order = (int*)carve((size_t)NN * 4);
    int*    bsum  = (int*)carve(64 * 4);
    int*    boff  = (int*)carve(64 * 4);
    int*    bins  = (int*)carve(128 * 4);                     // hist[64] + cur[64]
    int*    binoff= (int*)carve(64 * 4);
    int*    perm  = (int*)carve((size_t)EE * 4 + 64);
    size_t remain = (ws_size > off + 4096) ? (ws_size - off - 4096) : 0;
    long long maxNodes = (long long)(remain / 1024);          // 1 KB per node
    int chunkN = (maxNodes >= NN) ? NN : (int)maxNodes;
    if (chunkN < 512) chunkN = 512;
    chunkN = (chunkN + 63) & ~63;
    __bf16* aggF = (__bf16*)carve((size_t)chunkN * 512 * 2);
    int nch = (NN + chunkN - 1) / chunkN;

    // CSR build + degree sort
    k_zero<<<(NN + 255) / 256, 256, 0, stream>>>(deg, curs, bins);
    k_deg<<<(EE + 255) / 256, 256, 0, stream>>>(et, deg);
    k_scan1<<<49, 1024, 0, stream>>>(deg, incl, bsum);
    k_scan2<<<1, 64, 0, stream>>>(bsum, boff);
    k_scan3<<<49, 1024, 0, stream>>>(incl, deg, boff, rowst);
    k_fill<<<(EE + 255) / 256, 256, 0, stream>>>(et, rowst, curs, perm);
    k_hist<<<(NN + 255) / 256, 256, 0, stream>>>(deg, bins);
    k_binscan<<<1, 64, 0, stream>>>(bins, binoff);
    k_scatter<<<(NN + 255) / 256, 256, 0, stream>>>(deg, binoff, bins + 64, order);

    // weights + input projection
    k_prep<<<88, 256, 0, stream>>>(input_w, basis0, rootw0, basis1, rootw1, WtInF, WtF0, WtF1);
    k_gemm_in<<<(NN + 63) / 64, 256, 0, stream>>>(nf, WtInF, input_b, x0, NN);

    // layer 0
    for (int c = 0; c < nch; ++c) {
        int o0 = c * chunkN;
        int cnt = (o0 + chunkN <= NN) ? chunkN : (NN - o0);
        k_agg5<<<(cnt + 3) / 4, 256, 0, stream>>>(x0, perm, rowst, deg, att0, order, aggF, o0, cnt);
        k_gemm_layer<0><<<(cnt + 63) / 64, 256, 0, stream>>>(aggF, x0, WtF0, rootb0, lng0, lnb0,
                                                             order, x1, nullptr, o0, cnt);
    }

    // layer 1
    for (int c = 0; c < nch; ++c) {
        int o0 = c * chunkN;
        int cnt = (o0 + chunkN <= NN) ? chunkN : (NN - o0);
        k_agg5<<<(cnt + 3) / 4, 256, 0, stream>>>(x1, perm, rowst, deg, att1, order, aggF, o0, cnt);
        k_gemm_layer<1><<<(cnt + 63) / 64, 256, 0, stream>>>(aggF, x1, WtF1, rootb1, lng1, lnb1,
                                                             order, nullptr, (float*)d_out, o0, cnt);
    }
}

// Round 6
// 315.926 us; speedup vs baseline: 1.7662x; 1.7662x over previous
//
#include <hip/hip_runtime.h>
#include <hip/hip_bf16.h>

#define NN 50000
#define EE 800000
#define NBLK 196   // ceil(NN/256)

typedef __bf16 bf16x8 __attribute__((ext_vector_type(8)));
typedef float f32x4 __attribute__((ext_vector_type(4)));

__device__ inline float bf2f(unsigned int u) {
    union { unsigned int i; float f; } x; x.i = (u & 0xFFFFu) << 16; return x.f;
}
__device__ inline float bf2fh(unsigned int u) {
    union { unsigned int i; float f; } x; x.i = u & 0xFFFF0000u; return x.f;
}
__device__ inline void bf8_to_f(bf16x8 v, float* f) {
    const unsigned int* u = (const unsigned int*)&v;
    f[0] = bf2f(u[0]); f[1] = bf2fh(u[0]);
    f[2] = bf2f(u[1]); f[3] = bf2fh(u[1]);
    f[4] = bf2f(u[2]); f[5] = bf2fh(u[2]);
    f[6] = bf2f(u[3]); f[7] = bf2fh(u[3]);
}

// ---------------- zero deg/cursor (graph-safe) ----------------
__global__ void k_zero(int* __restrict__ deg, int* __restrict__ curs) {
    int i = blockIdx.x * 256 + threadIdx.x;
    if (i < NN) { deg[i] = 0; curs[i] = 0; }
}

// ---------------- CSR build ----------------
__global__ void k_deg(const int* __restrict__ et, int* __restrict__ deg) {
    int e = blockIdx.x * 256 + threadIdx.x;
    if (e < EE) atomicAdd(&deg[et[e * 3 + 2]], 1);
}

__global__ void k_scan1(const int* __restrict__ deg, int* __restrict__ incl, int* __restrict__ bsum) {
    __shared__ int s[1024];
    int i = blockIdx.x * 1024 + threadIdx.x;
    int v = (i < NN) ? deg[i] : 0;
    s[threadIdx.x] = v;
    __syncthreads();
    for (int off = 1; off < 1024; off <<= 1) {
        int t = (threadIdx.x >= off) ? s[threadIdx.x - off] : 0;
        __syncthreads();
        s[threadIdx.x] += t;
        __syncthreads();
    }
    if (i < NN) incl[i] = s[threadIdx.x];
    if (threadIdx.x == 1023) bsum[blockIdx.x] = s[1023];
}

__global__ void k_scan2(const int* __restrict__ bsum, int* __restrict__ boff) {
    if (threadIdx.x == 0 && blockIdx.x == 0) {
        int acc = 0;
        for (int i = 0; i < 49; ++i) { boff[i] = acc; acc += bsum[i]; }
    }
}

__global__ void k_scan3(const int* __restrict__ incl, const int* __restrict__ deg,
                        const int* __restrict__ boff, int* __restrict__ row_start) {
    int i = blockIdx.x * 1024 + threadIdx.x;
    if (i < NN) row_start[i] = incl[i] - deg[i] + boff[blockIdx.x];
}

__global__ void k_fill(const int* __restrict__ et, const int* __restrict__ row_start,
                       int* __restrict__ cursor, int* __restrict__ perm) {
    int e = blockIdx.x * 256 + threadIdx.x;
    if (e >= EE) return;
    int src = et[e * 3 + 0];
    int rel = et[e * 3 + 1];
    int dst = et[e * 3 + 2];
    int pos = row_start[dst] + atomicAdd(&cursor[dst], 1);
    perm[pos] = src | (rel << 16);      // src < 65536, rel < 16
}

// ---------------- degree counting-sort (descending), block-aggregated ----------------
__global__ void k_hist2(const int* __restrict__ deg, int* __restrict__ blockHist) {
    __shared__ int h[64];
    int t = threadIdx.x;
    if (t < 64) h[t] = 0;
    __syncthreads();
    int i = blockIdx.x * 256 + t;
    if (i < NN) {
        int d = deg[i]; d = d > 63 ? 63 : d;
        atomicAdd(&h[63 - d], 1);
    }
    __syncthreads();
    if (t < 64) blockHist[blockIdx.x * 64 + t] = h[t];
}

// one block of 64 threads; thread t = key t
__global__ void k_binscan2(const int* __restrict__ blockHist, int* __restrict__ blockBase,
                           int* __restrict__ binoff) {
    __shared__ int tot[64];
    int t = threadIdx.x;
    int acc = 0;
    for (int b = 0; b < NBLK; ++b) {
        blockBase[b * 64 + t] = acc;
        acc += blockHist[b * 64 + t];
    }
    tot[t] = acc;
    __syncthreads();
    if (t == 0) {
        int a = 0;
        for (int k = 0; k < 64; ++k) { binoff[k] = a; a += tot[k]; }
    }
    __syncthreads();
    int off = binoff[t];
    for (int b = 0; b < NBLK; ++b) blockBase[b * 64 + t] += off;
}

__global__ void k_scatter2(const int* __restrict__ deg, const int* __restrict__ blockBase,
                           int* __restrict__ order) {
    __shared__ int cur[64];
    int t = threadIdx.x;
    if (t < 64) cur[t] = blockBase[blockIdx.x * 64 + t];
    __syncthreads();
    int i = blockIdx.x * 256 + t;
    if (i < NN) {
        int d = deg[i]; d = d > 63 ? 63 : d;
        int key = 63 - d;
        int pos = atomicAdd(&cur[key], 1);
        order[pos] = i;
    }
}

// ---------------- fragment-major weight prep ----------------
__global__ void k_prep(const float* __restrict__ iw,
                       const float* __restrict__ basis0, const float* __restrict__ rootw0,
                       const float* __restrict__ basis1, const float* __restrict__ rootw1,
                       __bf16* __restrict__ WtInF, __bf16* __restrict__ WtF0, __bf16* __restrict__ WtF1) {
    int t = blockIdx.x * 256 + threadIdx.x;
    if (t < 2048) {
        int lane = t & 63, grp = t >> 6;       // grp = nblk*4+kk
        int kk = grp & 3, nblk = grp >> 2;
        int col = nblk * 16 + (lane & 15);
        int k0 = kk * 32 + (lane >> 4) * 8;
        bf16x8 v;
        #pragma unroll
        for (int j = 0; j < 8; ++j) v[j] = (__bf16)iw[(size_t)(k0 + j) * 128 + col];
        *(bf16x8*)(WtInF + (size_t)t * 8) = v;
        return;
    }
    t -= 2048;
    const float* basis = basis0; const float* rootw = rootw0; __bf16* W = WtF0;
    if (t >= 10240) { t -= 10240; basis = basis1; rootw = rootw1; W = WtF1; }
    if (t >= 10240) return;
    int lane = t & 63, grp = t >> 6;           // grp = nblk*20+kk
    int kk = grp % 20, nblk = grp / 20;
    int col = nblk * 16 + (lane & 15);
    int k0 = kk * 32 + (lane >> 4) * 8;
    bf16x8 v;
    #pragma unroll
    for (int j = 0; j < 8; ++j) {
        int k = k0 + j;
        float f = (k < 512) ? basis[(size_t)(k >> 7) * 16384 + (size_t)(k & 127) * 128 + col]
                            : rootw[(size_t)(k - 512) * 128 + col];
        v[j] = (__bf16)f;
    }
    *(bf16x8*)(W + (size_t)t * 8) = v;
}

// ---------------- input GEMM: x0 = nf(f32) @ input_w + b (bf16 out), 64-row tiles ----------------
__global__ void k_gemm_in(const float* __restrict__ A, const __bf16* __restrict__ WtInF,
                          const float* __restrict__ bias, __bf16* __restrict__ out, int M) {
    const int tid = threadIdx.x, wave = tid >> 6, lane = tid & 63;
    const int wr = wave >> 1, wc = wave & 1;
    const int l15 = lane & 15, lhi = lane >> 4;
    f32x4 acc[2][4] = {};
    #define LDAI(dst, KK) do { \
        _Pragma("unroll") \
        for (int m = 0; m < 2; ++m) { \
            int rw = blockIdx.x * 64 + wr * 32 + m * 16 + l15; \
            rw = rw < M ? rw : M - 1; \
            const float* ap = A + (size_t)rw * 128 + (KK) * 32 + lhi * 8; \
            float4 v0 = *(const float4*)ap, v1 = *(const float4*)(ap + 4); \
            bf16x8 f; \
            f[0]=(__bf16)v0.x; f[1]=(__bf16)v0.y; f[2]=(__bf16)v0.z; f[3]=(__bf16)v0.w; \
            f[4]=(__bf16)v1.x; f[5]=(__bf16)v1.y; f[6]=(__bf16)v1.z; f[7]=(__bf16)v1.w; \
            dst[m] = f; \
        } } while (0)
    #define LDBI(dst, KK) do { \
        _Pragma("unroll") \
        for (int n = 0; n < 4; ++n) \
            dst[n] = *(const bf16x8*)(WtInF + (((size_t)(wc * 4 + n) * 4 + (KK)) * 64 + lane) * 8); \
        } while (0)
    #define MMI(AA, BB) do { \
        _Pragma("unroll") for (int m = 0; m < 2; ++m) \
        _Pragma("unroll") for (int n = 0; n < 4; ++n) \
            acc[m][n] = __builtin_amdgcn_mfma_f32_16x16x32_bf16(AA[m], BB[n], acc[m][n], 0, 0, 0); \
        } while (0)
    bf16x8 aP[2], bP[4], aQ[2], bQ[4];
    LDAI(aP, 0); LDBI(bP, 0);
    #pragma unroll
    for (int tstep = 0; tstep < 2; ++tstep) {
        LDAI(aQ, 2 * tstep + 1); LDBI(bQ, 2 * tstep + 1);
        MMI(aP, bP);
        if (tstep < 1) { LDAI(aP, 2 * tstep + 2); LDBI(bP, 2 * tstep + 2); }
        MMI(aQ, bQ);
    }
    #pragma unroll
    for (int m = 0; m < 2; ++m)
        #pragma unroll
        for (int j = 0; j < 4; ++j) {
            int row = blockIdx.x * 64 + wr * 32 + m * 16 + lhi * 4 + j;
            if (row >= M) continue;
            #pragma unroll
            for (int n = 0; n < 4; ++n) {
                int col = wc * 64 + n * 16 + l15;
                out[(size_t)row * 128 + col] = (__bf16)(acc[m][n][j] + bias[col]);
            }
        }
}

// ---------------- gather + aggregate: degree-sorted, software-pipelined ----------------
__global__ void k_agg5(const __bf16* __restrict__ x, const int* __restrict__ perm,
                       const int* __restrict__ rowst, const int* __restrict__ deg,
                       const float* __restrict__ att, const int* __restrict__ order,
                       __bf16* __restrict__ aggF, int nodeOff, int nodeCnt) {
    __shared__ float4 satt[16];
    if (threadIdx.x < 16) satt[threadIdx.x] = ((const float4*)att)[threadIdx.x];
    __syncthreads();
    int local = blockIdx.x * 4 + (threadIdx.x >> 6);
    if (local >= nodeCnt) return;
    int lane = threadIdx.x & 63;
    int e4 = lane >> 4, c8 = lane & 15;
    int node = order[nodeOff + local];
    int start = rowst[node], cnt = deg[node];
    float acc[4][8] = {};
    int nIt = (cnt + 7) >> 3;
    if (nIt > 0) {
        bf16x8 uA, uB; float4 cA, cB;
        {
            int eA = e4, eB = e4 + 4;
            bool vA = eA < cnt, vB = eB < cnt;
            int pA = vA ? perm[start + eA] : 0;
            int pB = vB ? perm[start + eB] : 0;
            uA = *(const bf16x8*)(x + (size_t)(pA & 0xFFFF) * 128 + c8 * 8);
            uB = *(const bf16x8*)(x + (size_t)(pB & 0xFFFF) * 128 + c8 * 8);
            cA = vA ? satt[pA >> 16] : make_float4(0.f, 0.f, 0.f, 0.f);
            cB = vB ? satt[pB >> 16] : make_float4(0.f, 0.f, 0.f, 0.f);
        }
        for (int s = 0; ; ++s) {
            bf16x8 nA, nB; float4 nCA, nCB;
            bool more = (s + 1 < nIt);
            if (more) {
                int eA = (s + 1) * 8 + e4, eB = eA + 4;
                bool vA = eA < cnt, vB = eB < cnt;
                int pA = vA ? perm[start + eA] : 0;
                int pB = vB ? perm[start + eB] : 0;
                nA = *(const bf16x8*)(x + (size_t)(pA & 0xFFFF) * 128 + c8 * 8);
                nB = *(const bf16x8*)(x + (size_t)(pB & 0xFFFF) * 128 + c8 * 8);
                nCA = vA ? satt[pA >> 16] : make_float4(0.f, 0.f, 0.f, 0.f);
                nCB = vB ? satt[pB >> 16] : make_float4(0.f, 0.f, 0.f, 0.f);
            }
            float fA[8], fB[8];
            bf8_to_f(uA, fA);
            bf8_to_f(uB, fB);
            #pragma unroll
            for (int j = 0; j < 8; ++j) {
                acc[0][j] += cA.x * fA[j]; acc[1][j] += cA.y * fA[j];
                acc[2][j] += cA.z * fA[j]; acc[3][j] += cA.w * fA[j];
            }
            #pragma unroll
            for (int j = 0; j < 8; ++j) {
                acc[0][j] += cB.x * fB[j]; acc[1][j] += cB.y * fB[j];
                acc[2][j] += cB.z * fB[j]; acc[3][j] += cB.w * fB[j];
            }
            if (!more) break;
            uA = nA; uB = nB; cA = nCA; cB = nCB;
        }
    }
    float dinv = (cnt > 0) ? 1.f / (float)cnt : 0.f;
    #pragma unroll
    for (int b = 0; b < 4; ++b)
        #pragma unroll
        for (int j = 0; j < 8; ++j) {
            float v = acc[b][j];
            v += __shfl_xor(v, 16);
            v += __shfl_xor(v, 32);
            acc[b][j] = v * dinv;
        }
    bf16x8 o;
    #pragma unroll
    for (int j = 0; j < 8; ++j) {
        float v = (e4 == 0) ? acc[0][j] : (e4 == 1) ? acc[1][j] : (e4 == 2) ? acc[2][j] : acc[3][j];
        o[j] = (__bf16)v;
    }
    size_t idx8 = (((size_t)(local >> 4) * 16 + e4 * 4 + (c8 >> 2)) * 64 + (c8 & 3) * 16 + (local & 15)) * 8;
    *(bf16x8*)(aggF + idx8) = o;
}

// ---------------- layer GEMM over sorted positions; LN(+ReLU) fused ----------------
template<int OUTF>
__global__ void k_gemm_layer(const __bf16* __restrict__ aggF, const __bf16* __restrict__ x,
                             const __bf16* __restrict__ WtF, const float* __restrict__ rb,
                             const float* __restrict__ g, const float* __restrict__ bb,
                             const int* __restrict__ order,
                             __bf16* __restrict__ outB, float* __restrict__ outF,
                             int rowOff, int nodeCnt) {
    __shared__ float red[2][2][64];
    __shared__ float murs[2][64];
    const int tid = threadIdx.x, wave = tid >> 6, lane = tid & 63;
    const int wr = wave >> 1, wc = wave & 1;
    const int l15 = lane & 15, lhi = lane >> 4;
    const int rowgrpBase = blockIdx.x * 4 + wr * 2;
    int ordm[2];
    #pragma unroll
    for (int m = 0; m < 2; ++m) {
        int rw = blockIdx.x * 64 + wr * 32 + m * 16 + l15;
        rw = rw < nodeCnt ? rw : nodeCnt - 1;
        ordm[m] = order[rowOff + rw];
    }
    f32x4 acc[2][4] = {};
    #define LDA(dst, KK) do { \
        _Pragma("unroll") \
        for (int m = 0; m < 2; ++m) { \
            if ((KK) < 16) { \
                dst[m] = *(const bf16x8*)(aggF + (((size_t)(rowgrpBase + m) * 16 + (KK)) * 64 + lane) * 8); \
            } else { \
                dst[m] = *(const bf16x8*)(x + (size_t)ordm[m] * 128 + ((KK) - 16) * 32 + lhi * 8); \
            } \
        } } while (0)
    #define LDB(dst, KK) do { \
        _Pragma("unroll") \
        for (int n = 0; n < 4; ++n) \
            dst[n] = *(const bf16x8*)(WtF + (((size_t)(wc * 4 + n) * 20 + (KK)) * 64 + lane) * 8); \
        } while (0)
    #define MM(AA, BB) do { \
        _Pragma("unroll") for (int m = 0; m < 2; ++m) \
        _Pragma("unroll") for (int n = 0; n < 4; ++n) \
            acc[m][n] = __builtin_amdgcn_mfma_f32_16x16x32_bf16(AA[m], BB[n], acc[m][n], 0, 0, 0); \
        } while (0)
    bf16x8 aP[2], bP[4], aQ[2], bQ[4];
    LDA(aP, 0); LDB(bP, 0);
    #pragma unroll
    for (int t = 0; t < 10; ++t) {
        LDA(aQ, 2 * t + 1); LDB(bQ, 2 * t + 1);
        MM(aP, bP);
        if (t < 9) { LDA(aP, 2 * t + 2); LDB(bP, 2 * t + 2); }
        MM(aQ, bQ);
    }
    float colb[4];
    #pragma unroll
    for (int n = 0; n < 4; ++n) colb[n] = rb[wc * 64 + n * 16 + l15];
    #pragma unroll
    for (int m = 0; m < 2; ++m)
        #pragma unroll
        for (int j = 0; j < 4; ++j) {
            float s = 0.f, q = 0.f;
            #pragma unroll
            for (int n = 0; n < 4; ++n) {
                float v = acc[m][n][j] + colb[n];
                acc[m][n][j] = v;
                s += v; q += v * v;
            }
            #pragma unroll
            for (int o = 1; o < 16; o <<= 1) { s += __shfl_xor(s, o); q += __shfl_xor(q, o); }
            if (l15 == 0) {
                int r = wr * 32 + m * 16 + lhi * 4 + j;
                red[0][wc][r] = s; red[1][wc][r] = q;
            }
        }
    __syncthreads();
    if (tid < 64) {
        float s = red[0][0][tid] + red[0][1][tid];
        float q = red[1][0][tid] + red[1][1][tid];
        float mu = s * (1.f / 128.f);
        float var = q * (1.f / 128.f) - mu * mu;
        murs[0][tid] = mu;
        murs[1][tid] = rsqrtf(var + 1e-5f);
    }
    __syncthreads();
    float gg[4], gb[4];
    #pragma unroll
    for (int n = 0; n < 4; ++n) {
        int col = wc * 64 + n * 16 + l15;
        gg[n] = g[col]; gb[n] = bb[col];
    }
    #pragma unroll
    for (int m = 0; m < 2; ++m)
        #pragma unroll
        for (int j = 0; j < 4; ++j) {
            int rblk = wr * 32 + m * 16 + lhi * 4 + j;
            int lr = blockIdx.x * 64 + rblk;
            if (lr >= nodeCnt) continue;
            float mu = murs[0][rblk], rs = murs[1][rblk];
            int ord = order[rowOff + lr];
            size_t rowbase = (size_t)ord * 128;
            #pragma unroll
            for (int n = 0; n < 4; ++n) {
                int col = wc * 64 + n * 16 + l15;
                float v = (acc[m][n][j] - mu) * rs * gg[n] + gb[n];
                if (OUTF == 0) { v = fmaxf(v, 0.f); outB[rowbase + col] = (__bf16)v; }
                else           { outF[rowbase + col] = v; }
            }
        }
}

// ---------------- launch ----------------
extern "C" void kernel_launch(void* const* d_in, const int* in_sizes, int n_in,
                              void* d_out, int out_size, void* d_ws, size_t ws_size,
                              hipStream_t stream) {
    const float* nf      = (const float*)d_in[0];
    const int*   et      = (const int*)d_in[1];
    const float* input_w = (const float*)d_in[3];
    const float* input_b = (const float*)d_in[4];
    const float* basis0  = (const float*)d_in[5];
    const float* att0    = (const float*)d_in[6];
    const float* rootw0  = (const float*)d_in[7];
    const float* rootb0  = (const float*)d_in[8];
    const float* lng0    = (const float*)d_in[9];
    const float* lnb0    = (const float*)d_in[10];
    const float* basis1  = (const float*)d_in[11];
    const float* att1    = (const float*)d_in[12];
    const float* rootw1  = (const float*)d_in[13];
    const float* rootb1  = (const float*)d_in[14];
    const float* lng1    = (const float*)d_in[15];
    const float* lnb1    = (const float*)d_in[16];
    (void)in_sizes; (void)n_in; (void)out_size;

    char* ws = (char*)d_ws;
    size_t off = 0;
    auto carve = [&](size_t bytes) { char* p = ws + off; off = (off + bytes + 255) & ~(size_t)255; return p; };
    __bf16* x0    = (__bf16*)carve((size_t)NN * 128 * 2);
    __bf16* x1    = (__bf16*)carve((size_t)NN * 128 * 2);
    __bf16* WtInF = (__bf16*)carve((size_t)128 * 128 * 2);
    __bf16* WtF0  = (__bf16*)carve((size_t)128 * 640 * 2);
    __bf16* WtF1  = (__bf16*)carve((size_t)128 * 640 * 2);
    int*    deg   = (int*)carve((size_t)NN * 4);
    int*    incl  = (int*)carve((size_t)NN * 4);
    int*    rowst = (int*)carve((size_t)NN * 4);
    int*    curs  = (int*)carve((size_t)NN * 4);
    int*    order = (int*)carve((size_t)NN * 4);
    int*    bsum  = (int*)carve(64 * 4);
    int*    boff  = (int*)carve(64 * 4);
    int*    blockHist = (int*)carve((size_t)NBLK * 64 * 4);
    int*    blockBase = (int*)carve((size_t)NBLK * 64 * 4);
    int*    binoff    = (int*)carve(64 * 4);
    int*    perm  = (int*)carve((size_t)EE * 4 + 64);
    size_t remain = (ws_size > off + 4096) ? (ws_size - off - 4096) : 0;
    long long maxNodes = (long long)(remain / 1024);
    int chunkN = (maxNodes >= NN) ? NN : (int)maxNodes;
    if (chunkN < 512) chunkN = 512;
    chunkN = (chunkN + 63) & ~63;
    __bf16* aggF = (__bf16*)carve((size_t)chunkN * 512 * 2);
    int nch = (NN + chunkN - 1) / chunkN;

    // CSR build + degree sort (block-aggregated counting sort)
    k_zero<<<NBLK, 256, 0, stream>>>(deg, curs);
    k_deg<<<(EE + 255) / 256, 256, 0, stream>>>(et, deg);
    k_scan1<<<49, 1024, 0, stream>>>(deg, incl, bsum);
    k_scan2<<<1, 64, 0, stream>>>(bsum, boff);
    k_scan3<<<49, 1024, 0, stream>>>(incl, deg, boff, rowst);
    k_fill<<<(EE + 255) / 256, 256, 0, stream>>>(et, rowst, curs, perm);
    k_hist2<<<NBLK, 256, 0, stream>>>(deg, blockHist);
    k_binscan2<<<1, 64, 0, stream>>>(blockHist, blockBase, binoff);
    k_scatter2<<<NBLK, 256, 0, stream>>>(deg, blockBase, order);

    // weights + input projection
    k_prep<<<88, 256, 0, stream>>>(input_w, basis0, rootw0, basis1, rootw1, WtInF, WtF0, WtF1);
    k_gemm_in<<<(NN + 63) / 64, 256, 0, stream>>>(nf, WtInF, input_b, x0, NN);

    // layer 0
    for (int c = 0; c < nch; ++c) {
        int o0 = c * chunkN;
        int cnt = (o0 + chunkN <= NN) ? chunkN : (NN - o0);
        k_agg5<<<(cnt + 3) / 4, 256, 0, stream>>>(x0, perm, rowst, deg, att0, order, aggF, o0, cnt);
        k_gemm_layer<0><<<(cnt + 63) / 64, 256, 0, stream>>>(aggF, x0, WtF0, rootb0, lng0, lnb0,
                                                             order, x1, nullptr, o0, cnt);
    }

    // layer 1
    for (int c = 0; c < nch; ++c) {
        int o0 = c * chunkN;
        int cnt = (o0 + chunkN <= NN) ? chunkN : (NN - o0);
        k_agg5<<<(cnt + 3) / 4, 256, 0, stream>>>(x1, perm, rowst, deg, att1, order, aggF, o0, cnt);
        k_gemm_layer<1><<<(cnt + 63) / 64, 256, 0, stream>>>(aggF, x1, WtF1, rootb1, lng1, lnb1,
                                                             order, nullptr, (float*)d_out, o0, cnt);
    }
}

// Round 7
// 279.151 us; speedup vs baseline: 1.9988x; 1.1317x over previous
//
#include <hip/hip_runtime.h>
#include <hip/hip_bf16.h>

#define NN 50000
#define EE 800000
#define NBLK 196   // ceil(NN/256)

typedef __bf16 bf16x8 __attribute__((ext_vector_type(8)));
typedef float f32x4 __attribute__((ext_vector_type(4)));

__device__ inline float bf2f(unsigned int u) {
    union { unsigned int i; float f; } x; x.i = (u & 0xFFFFu) << 16; return x.f;
}
__device__ inline float bf2fh(unsigned int u) {
    union { unsigned int i; float f; } x; x.i = u & 0xFFFF0000u; return x.f;
}
__device__ inline void bf8_to_f(bf16x8 v, float* f) {
    const unsigned int* u = (const unsigned int*)&v;
    f[0] = bf2f(u[0]); f[1] = bf2fh(u[0]);
    f[2] = bf2f(u[1]); f[3] = bf2fh(u[1]);
    f[4] = bf2f(u[2]); f[5] = bf2fh(u[2]);
    f[6] = bf2f(u[3]); f[7] = bf2fh(u[3]);
}

// ---------------- zero deg/cursor (graph-safe) ----------------
__global__ void k_zero(int* __restrict__ deg, int* __restrict__ curs) {
    int i = blockIdx.x * 256 + threadIdx.x;
    if (i < NN) { deg[i] = 0; curs[i] = 0; }
}

// ---------------- CSR build ----------------
__global__ void k_deg(const int* __restrict__ et, int* __restrict__ deg) {
    int e = blockIdx.x * 256 + threadIdx.x;
    if (e < EE) atomicAdd(&deg[et[e * 3 + 2]], 1);
}

__global__ void k_scan1(const int* __restrict__ deg, int* __restrict__ incl, int* __restrict__ bsum) {
    __shared__ int s[1024];
    int i = blockIdx.x * 1024 + threadIdx.x;
    int v = (i < NN) ? deg[i] : 0;
    s[threadIdx.x] = v;
    __syncthreads();
    for (int off = 1; off < 1024; off <<= 1) {
        int t = (threadIdx.x >= off) ? s[threadIdx.x - off] : 0;
        __syncthreads();
        s[threadIdx.x] += t;
        __syncthreads();
    }
    if (i < NN) incl[i] = s[threadIdx.x];
    if (threadIdx.x == 1023) bsum[blockIdx.x] = s[1023];
}

__global__ void k_scan2(const int* __restrict__ bsum, int* __restrict__ boff) {
    if (threadIdx.x == 0 && blockIdx.x == 0) {
        int acc = 0;
        for (int i = 0; i < 49; ++i) { boff[i] = acc; acc += bsum[i]; }
    }
}

__global__ void k_scan3(const int* __restrict__ incl, const int* __restrict__ deg,
                        const int* __restrict__ boff, int* __restrict__ row_start) {
    int i = blockIdx.x * 1024 + threadIdx.x;
    if (i < NN) row_start[i] = incl[i] - deg[i] + boff[blockIdx.x];
}

__global__ void k_fill(const int* __restrict__ et, const int* __restrict__ row_start,
                       int* __restrict__ cursor, int* __restrict__ perm) {
    int e = blockIdx.x * 256 + threadIdx.x;
    if (e >= EE) return;
    int src = et[e * 3 + 0];
    int rel = et[e * 3 + 1];
    int dst = et[e * 3 + 2];
    int pos = row_start[dst] + atomicAdd(&cursor[dst], 1);
    perm[pos] = src | (rel << 16);      // src < 65536, rel < 16
}

// ---------------- fragment-major weight prep ----------------
__global__ void k_prep(const float* __restrict__ iw,
                       const float* __restrict__ basis0, const float* __restrict__ rootw0,
                       const float* __restrict__ basis1, const float* __restrict__ rootw1,
                       __bf16* __restrict__ WtInF, __bf16* __restrict__ WtF0, __bf16* __restrict__ WtF1) {
    int t = blockIdx.x * 256 + threadIdx.x;
    if (t < 2048) {
        int lane = t & 63, grp = t >> 6;       // grp = nblk*4+kk
        int kk = grp & 3, nblk = grp >> 2;
        int col = nblk * 16 + (lane & 15);
        int k0 = kk * 32 + (lane >> 4) * 8;
        bf16x8 v;
        #pragma unroll
        for (int j = 0; j < 8; ++j) v[j] = (__bf16)iw[(size_t)(k0 + j) * 128 + col];
        *(bf16x8*)(WtInF + (size_t)t * 8) = v;
        return;
    }
    t -= 2048;
    const float* basis = basis0; const float* rootw = rootw0; __bf16* W = WtF0;
    if (t >= 10240) { t -= 10240; basis = basis1; rootw = rootw1; W = WtF1; }
    if (t >= 10240) return;
    int lane = t & 63, grp = t >> 6;           // grp = nblk*20+kk
    int kk = grp % 20, nblk = grp / 20;
    int col = nblk * 16 + (lane & 15);
    int k0 = kk * 32 + (lane >> 4) * 8;
    bf16x8 v;
    #pragma unroll
    for (int j = 0; j < 8; ++j) {
        int k = k0 + j;
        float f = (k < 512) ? basis[(size_t)(k >> 7) * 16384 + (size_t)(k & 127) * 128 + col]
                            : rootw[(size_t)(k - 512) * 128 + col];
        v[j] = (__bf16)f;
    }
    *(bf16x8*)(W + (size_t)t * 8) = v;
}

// ---------------- input GEMM: x0 = nf(f32) @ input_w + b (bf16 out), 64-row tiles ----------------
__global__ void k_gemm_in(const float* __restrict__ A, const __bf16* __restrict__ WtInF,
                          const float* __restrict__ bias, __bf16* __restrict__ out, int M) {
    const int tid = threadIdx.x, wave = tid >> 6, lane = tid & 63;
    const int wr = wave >> 1, wc = wave & 1;
    const int l15 = lane & 15, lhi = lane >> 4;
    f32x4 acc[2][4] = {};
    #define LDAI(dst, KK) do { \
        _Pragma("unroll") \
        for (int m = 0; m < 2; ++m) { \
            int rw = blockIdx.x * 64 + wr * 32 + m * 16 + l15; \
            rw = rw < M ? rw : M - 1; \
            const float* ap = A + (size_t)rw * 128 + (KK) * 32 + lhi * 8; \
            float4 v0 = *(const float4*)ap, v1 = *(const float4*)(ap + 4); \
            bf16x8 f; \
            f[0]=(__bf16)v0.x; f[1]=(__bf16)v0.y; f[2]=(__bf16)v0.z; f[3]=(__bf16)v0.w; \
            f[4]=(__bf16)v1.x; f[5]=(__bf16)v1.y; f[6]=(__bf16)v1.z; f[7]=(__bf16)v1.w; \
            dst[m] = f; \
        } } while (0)
    #define LDBI(dst, KK) do { \
        _Pragma("unroll") \
        for (int n = 0; n < 4; ++n) \
            dst[n] = *(const bf16x8*)(WtInF + (((size_t)(wc * 4 + n) * 4 + (KK)) * 64 + lane) * 8); \
        } while (0)
    #define MMI(AA, BB) do { \
        _Pragma("unroll") for (int m = 0; m < 2; ++m) \
        _Pragma("unroll") for (int n = 0; n < 4; ++n) \
            acc[m][n] = __builtin_amdgcn_mfma_f32_16x16x32_bf16(AA[m], BB[n], acc[m][n], 0, 0, 0); \
        } while (0)
    bf16x8 aP[2], bP[4], aQ[2], bQ[4];
    LDAI(aP, 0); LDBI(bP, 0);
    #pragma unroll
    for (int tstep = 0; tstep < 2; ++tstep) {
        LDAI(aQ, 2 * tstep + 1); LDBI(bQ, 2 * tstep + 1);
        MMI(aP, bP);
        if (tstep < 1) { LDAI(aP, 2 * tstep + 2); LDBI(bP, 2 * tstep + 2); }
        MMI(aQ, bQ);
    }
    #pragma unroll
    for (int m = 0; m < 2; ++m)
        #pragma unroll
        for (int j = 0; j < 4; ++j) {
            int row = blockIdx.x * 64 + wr * 32 + m * 16 + lhi * 4 + j;
            if (row >= M) continue;
            #pragma unroll
            for (int n = 0; n < 4; ++n) {
                int col = wc * 64 + n * 16 + l15;
                out[(size_t)row * 128 + col] = (__bf16)(acc[m][n][j] + bias[col]);
            }
        }
}

// ---------------- gather + aggregate: 16 edges in flight per wave ----------------
// one wave per dst node (natural order); 16 lanes per edge (lane owns 8 channels);
// per step, edges e4+4j (j=0..3): 4 independent gathers per lane issued before any FMA.
__global__ void k_agg6(const __bf16* __restrict__ x, const int* __restrict__ perm,
                       const int* __restrict__ rowst, const int* __restrict__ deg,
                       const float* __restrict__ att, __bf16* __restrict__ aggF,
                       int nodeOff, int nodeCnt) {
    __shared__ float4 satt[16];
    if (threadIdx.x < 16) satt[threadIdx.x] = ((const float4*)att)[threadIdx.x];
    __syncthreads();
    int local = blockIdx.x * 4 + (threadIdx.x >> 6);
    if (local >= nodeCnt) return;
    int lane = threadIdx.x & 63;
    int e4 = lane >> 4, c8 = lane & 15;
    int node = nodeOff + local;
    int start = rowst[node], cnt = deg[node];
    float acc[4][8] = {};
    int nSteps = (cnt + 15) >> 4;
    for (int s = 0; s < nSteps; ++s) {
        int p[4];
        bool valid[4];
        #pragma unroll
        for (int j = 0; j < 4; ++j) {
            int e = s * 16 + j * 4 + e4;
            valid[j] = e < cnt;
            p[j] = valid[j] ? perm[start + e] : 0;
        }
        bf16x8 u[4];
        #pragma unroll
        for (int j = 0; j < 4; ++j)
            u[j] = *(const bf16x8*)(x + (size_t)(p[j] & 0xFFFF) * 128 + c8 * 8);
        float4 cf[4];
        #pragma unroll
        for (int j = 0; j < 4; ++j)
            cf[j] = valid[j] ? satt[p[j] >> 16] : make_float4(0.f, 0.f, 0.f, 0.f);
        #pragma unroll
        for (int j = 0; j < 4; ++j) {
            float f[8];
            bf8_to_f(u[j], f);
            #pragma unroll
            for (int q = 0; q < 8; ++q) {
                acc[0][q] += cf[j].x * f[q];
                acc[1][q] += cf[j].y * f[q];
                acc[2][q] += cf[j].z * f[q];
                acc[3][q] += cf[j].w * f[q];
            }
        }
    }
    float dinv = (cnt > 0) ? 1.f / (float)cnt : 0.f;
    #pragma unroll
    for (int b = 0; b < 4; ++b)
        #pragma unroll
        for (int j = 0; j < 8; ++j) {
            float v = acc[b][j];
            v += __shfl_xor(v, 16);
            v += __shfl_xor(v, 32);
            acc[b][j] = v * dinv;
        }
    bf16x8 o;
    #pragma unroll
    for (int j = 0; j < 8; ++j) {
        float v = (e4 == 0) ? acc[0][j] : (e4 == 1) ? acc[1][j] : (e4 == 2) ? acc[2][j] : acc[3][j];
        o[j] = (__bf16)v;
    }
    size_t idx8 = (((size_t)(local >> 4) * 16 + e4 * 4 + (c8 >> 2)) * 64 + (c8 & 3) * 16 + (local & 15)) * 8;
    *(bf16x8*)(aggF + idx8) = o;
}

// ---------------- layer GEMM: y = [agg | x] @ W + rb ; LN(+ReLU) fused; 64-row tiles ----------------
template<int OUTF>
__global__ void k_gemm_layer(const __bf16* __restrict__ aggF, const __bf16* __restrict__ x,
                             const __bf16* __restrict__ WtF, const float* __restrict__ rb,
                             const float* __restrict__ g, const float* __restrict__ bb,
                             __bf16* __restrict__ outB, float* __restrict__ outF,
                             int rowOff, int nodeCnt) {
    __shared__ float red[2][2][64];
    __shared__ float murs[2][64];
    const int tid = threadIdx.x, wave = tid >> 6, lane = tid & 63;
    const int wr = wave >> 1, wc = wave & 1;
    const int l15 = lane & 15, lhi = lane >> 4;
    const int rowgrpBase = blockIdx.x * 4 + wr * 2;   // 16-node fragment groups
    f32x4 acc[2][4] = {};
    #define LDA(dst, KK) do { \
        _Pragma("unroll") \
        for (int m = 0; m < 2; ++m) { \
            if ((KK) < 16) { \
                dst[m] = *(const bf16x8*)(aggF + (((size_t)(rowgrpBase + m) * 16 + (KK)) * 64 + lane) * 8); \
            } else { \
                int rw = blockIdx.x * 64 + wr * 32 + m * 16 + l15; \
                rw = rw < nodeCnt ? rw : nodeCnt - 1; \
                dst[m] = *(const bf16x8*)(x + (size_t)(rowOff + rw) * 128 + ((KK) - 16) * 32 + lhi * 8); \
            } \
        } } while (0)
    #define LDB(dst, KK) do { \
        _Pragma("unroll") \
        for (int n = 0; n < 4; ++n) \
            dst[n] = *(const bf16x8*)(WtF + (((size_t)(wc * 4 + n) * 20 + (KK)) * 64 + lane) * 8); \
        } while (0)
    #define MM(AA, BB) do { \
        _Pragma("unroll") for (int m = 0; m < 2; ++m) \
        _Pragma("unroll") for (int n = 0; n < 4; ++n) \
            acc[m][n] = __builtin_amdgcn_mfma_f32_16x16x32_bf16(AA[m], BB[n], acc[m][n], 0, 0, 0); \
        } while (0)
    bf16x8 aP[2], bP[4], aQ[2], bQ[4];
    LDA(aP, 0); LDB(bP, 0);
    #pragma unroll
    for (int t = 0; t < 10; ++t) {
        LDA(aQ, 2 * t + 1); LDB(bQ, 2 * t + 1);
        MM(aP, bP);
        if (t < 9) { LDA(aP, 2 * t + 2); LDB(bP, 2 * t + 2); }
        MM(aQ, bQ);
    }
    float colb[4];
    #pragma unroll
    for (int n = 0; n < 4; ++n) colb[n] = rb[wc * 64 + n * 16 + l15];
    #pragma unroll
    for (int m = 0; m < 2; ++m)
        #pragma unroll
        for (int j = 0; j < 4; ++j) {
            float s = 0.f, q = 0.f;
            #pragma unroll
            for (int n = 0; n < 4; ++n) {
                float v = acc[m][n][j] + colb[n];
                acc[m][n][j] = v;
                s += v; q += v * v;
            }
            #pragma unroll
            for (int o = 1; o < 16; o <<= 1) { s += __shfl_xor(s, o); q += __shfl_xor(q, o); }
            if (l15 == 0) {
                int r = wr * 32 + m * 16 + lhi * 4 + j;
                red[0][wc][r] = s; red[1][wc][r] = q;
            }
        }
    __syncthreads();
    if (tid < 64) {
        float s = red[0][0][tid] + red[0][1][tid];
        float q = red[1][0][tid] + red[1][1][tid];
        float mu = s * (1.f / 128.f);
        float var = q * (1.f / 128.f) - mu * mu;
        murs[0][tid] = mu;
        murs[1][tid] = rsqrtf(var + 1e-5f);
    }
    __syncthreads();
    float gg[4], gb[4];
    #pragma unroll
    for (int n = 0; n < 4; ++n) {
        int col = wc * 64 + n * 16 + l15;
        gg[n] = g[col]; gb[n] = bb[col];
    }
    #pragma unroll
    for (int m = 0; m < 2; ++m)
        #pragma unroll
        for (int j = 0; j < 4; ++j) {
            int rblk = wr * 32 + m * 16 + lhi * 4 + j;
            int lr = blockIdx.x * 64 + rblk;
            if (lr >= nodeCnt) continue;
            float mu = murs[0][rblk], rs = murs[1][rblk];
            size_t rowbase = (size_t)(rowOff + lr) * 128;
            #pragma unroll
            for (int n = 0; n < 4; ++n) {
                int col = wc * 64 + n * 16 + l15;
                float v = (acc[m][n][j] - mu) * rs * gg[n] + gb[n];
                if (OUTF == 0) { v = fmaxf(v, 0.f); outB[rowbase + col] = (__bf16)v; }
                else           { outF[rowbase + col] = v; }
            }
        }
}

// ---------------- launch ----------------
extern "C" void kernel_launch(void* const* d_in, const int* in_sizes, int n_in,
                              void* d_out, int out_size, void* d_ws, size_t ws_size,
                              hipStream_t stream) {
    const float* nf      = (const float*)d_in[0];
    const int*   et      = (const int*)d_in[1];
    const float* input_w = (const float*)d_in[3];
    const float* input_b = (const float*)d_in[4];
    const float* basis0  = (const float*)d_in[5];
    const float* att0    = (const float*)d_in[6];
    const float* rootw0  = (const float*)d_in[7];
    const float* rootb0  = (const float*)d_in[8];
    const float* lng0    = (const float*)d_in[9];
    const float* lnb0    = (const float*)d_in[10];
    const float* basis1  = (const float*)d_in[11];
    const float* att1    = (const float*)d_in[12];
    const float* rootw1  = (const float*)d_in[13];
    const float* rootb1  = (const float*)d_in[14];
    const float* lng1    = (const float*)d_in[15];
    const float* lnb1    = (const float*)d_in[16];
    (void)in_sizes; (void)n_in; (void)out_size;

    char* ws = (char*)d_ws;
    size_t off = 0;
    auto carve = [&](size_t bytes) { char* p = ws + off; off = (off + bytes + 255) & ~(size_t)255; return p; };
    __bf16* x0    = (__bf16*)carve((size_t)NN * 128 * 2);
    __bf16* x1    = (__bf16*)carve((size_t)NN * 128 * 2);
    __bf16* WtInF = (__bf16*)carve((size_t)128 * 128 * 2);
    __bf16* WtF0  = (__bf16*)carve((size_t)128 * 640 * 2);
    __bf16* WtF1  = (__bf16*)carve((size_t)128 * 640 * 2);
    int*    deg   = (int*)carve((size_t)NN * 4);
    int*    incl  = (int*)carve((size_t)NN * 4);
    int*    rowst = (int*)carve((size_t)NN * 4);
    int*    curs  = (int*)carve((size_t)NN * 4);
    int*    bsum  = (int*)carve(64 * 4);
    int*    boff  = (int*)carve(64 * 4);
    int*    perm  = (int*)carve((size_t)EE * 4 + 64);
    size_t remain = (ws_size > off + 4096) ? (ws_size - off - 4096) : 0;
    long long maxNodes = (long long)(remain / 1024);
    int chunkN = (maxNodes >= NN) ? NN : (int)maxNodes;
    if (chunkN < 512) chunkN = 512;
    chunkN = (chunkN + 63) & ~63;
    __bf16* aggF = (__bf16*)carve((size_t)chunkN * 512 * 2);
    int nch = (NN + chunkN - 1) / chunkN;

    // CSR build
    k_zero<<<NBLK, 256, 0, stream>>>(deg, curs);
    k_deg<<<(EE + 255) / 256, 256, 0, stream>>>(et, deg);
    k_scan1<<<49, 1024, 0, stream>>>(deg, incl, bsum);
    k_scan2<<<1, 64, 0, stream>>>(bsum, boff);
    k_scan3<<<49, 1024, 0, stream>>>(incl, deg, boff, rowst);
    k_fill<<<(EE + 255) / 256, 256, 0, stream>>>(et, rowst, curs, perm);

    // weights + input projection
    k_prep<<<88, 256, 0, stream>>>(input_w, basis0, rootw0, basis1, rootw1, WtInF, WtF0, WtF1);
    k_gemm_in<<<(NN + 63) / 64, 256, 0, stream>>>(nf, WtInF, input_b, x0, NN);

    // layer 0
    for (int c = 0; c < nch; ++c) {
        int o0 = c * chunkN;
        int cnt = (o0 + chunkN <= NN) ? chunkN : (NN - o0);
        k_agg6<<<(cnt + 3) / 4, 256, 0, stream>>>(x0, perm, rowst, deg, att0, aggF, o0, cnt);
        k_gemm_layer<0><<<(cnt + 63) / 64, 256, 0, stream>>>(aggF, x0, WtF0, rootb0, lng0, lnb0,
                                                             x1, nullptr, o0, cnt);
    }

    // layer 1
    for (int c = 0; c < nch; ++c) {
        int o0 = c * chunkN;
        int cnt = (o0 + chunkN <= NN) ? chunkN : (NN - o0);
        k_agg6<<<(cnt + 3) / 4, 256, 0, stream>>>(x1, perm, rowst, deg, att1, aggF, o0, cnt);
        k_gemm_layer<1><<<(cnt + 63) / 64, 256, 0, stream>>>(aggF, x1, WtF1, rootb1, lng1, lnb1,
                                                             nullptr, (float*)d_out, o0, cnt);
    }
}

// Round 8
// 268.372 us; speedup vs baseline: 2.0791x; 1.0402x over previous
//
#include <hip/hip_runtime.h>
#include <hip/hip_bf16.h>
#include <hip/hip_fp8.h>

#define NN 50000
#define EE 800000
#define NBLK 196   // ceil(NN/256)

typedef __bf16 bf16x8 __attribute__((ext_vector_type(8)));
typedef float f32x4 __attribute__((ext_vector_type(4)));

__device__ inline float bf2f(unsigned int u) {
    union { unsigned int i; float f; } x; x.i = (u & 0xFFFFu) << 16; return x.f;
}
__device__ inline float bf2fh(unsigned int u) {
    union { unsigned int i; float f; } x; x.i = u & 0xFFFF0000u; return x.f;
}
__device__ inline void bf8_to_f(bf16x8 v, float* f) {
    const unsigned int* u = (const unsigned int*)&v;
    f[0] = bf2f(u[0]); f[1] = bf2fh(u[0]);
    f[2] = bf2f(u[1]); f[3] = bf2fh(u[1]);
    f[4] = bf2f(u[2]); f[5] = bf2fh(u[2]);
    f[6] = bf2f(u[3]); f[7] = bf2fh(u[3]);
}

// ---- fp8 e4m3 helpers (HW cvt on gfx950; hedged fallback to hip_fp8 types) ----
__device__ inline void fp8x8_to_f(uint2 w, float* f) {
#if __has_builtin(__builtin_amdgcn_cvt_f32_fp8)
    f[0] = __builtin_amdgcn_cvt_f32_fp8(w.x, 0);
    f[1] = __builtin_amdgcn_cvt_f32_fp8(w.x, 1);
    f[2] = __builtin_amdgcn_cvt_f32_fp8(w.x, 2);
    f[3] = __builtin_amdgcn_cvt_f32_fp8(w.x, 3);
    f[4] = __builtin_amdgcn_cvt_f32_fp8(w.y, 0);
    f[5] = __builtin_amdgcn_cvt_f32_fp8(w.y, 1);
    f[6] = __builtin_amdgcn_cvt_f32_fp8(w.y, 2);
    f[7] = __builtin_amdgcn_cvt_f32_fp8(w.y, 3);
#else
    const unsigned char* b = (const unsigned char*)&w;
    #pragma unroll
    for (int j = 0; j < 8; ++j) { __hip_fp8_e4m3 v; v.__x = b[j]; f[j] = float(v); }
#endif
}
__device__ inline uint2 f8_pack(const float* f) {
#if __has_builtin(__builtin_amdgcn_cvt_pk_fp8_f32)
    unsigned int lo = __builtin_amdgcn_cvt_pk_fp8_f32(f[0], f[1], 0u, false);
    lo = __builtin_amdgcn_cvt_pk_fp8_f32(f[2], f[3], lo, true);
    unsigned int hi = __builtin_amdgcn_cvt_pk_fp8_f32(f[4], f[5], 0u, false);
    hi = __builtin_amdgcn_cvt_pk_fp8_f32(f[6], f[7], hi, true);
    return make_uint2(lo, hi);
#else
    unsigned char b[8];
    #pragma unroll
    for (int j = 0; j < 8; ++j) { __hip_fp8_e4m3 v(f[j]); b[j] = v.__x; }
    return *(uint2*)b;
#endif
}

// ---------------- bf16 -> fp8 shadow copy (streaming, coalesced) ----------------
__global__ void k_cvt8(const __bf16* __restrict__ in, unsigned char* __restrict__ out, int n8) {
    int i = blockIdx.x * 256 + threadIdx.x;
    if (i >= n8) return;
    bf16x8 v = ((const bf16x8*)in)[i];
    float f[8];
    bf8_to_f(v, f);
    ((uint2*)out)[i] = f8_pack(f);
}

// ---------------- zero deg/cursor (graph-safe) ----------------
__global__ void k_zero(int* __restrict__ deg, int* __restrict__ curs) {
    int i = blockIdx.x * 256 + threadIdx.x;
    if (i < NN) { deg[i] = 0; curs[i] = 0; }
}

// ---------------- CSR build ----------------
__global__ void k_deg(const int* __restrict__ et, int* __restrict__ deg) {
    int e = blockIdx.x * 256 + threadIdx.x;
    if (e < EE) atomicAdd(&deg[et[e * 3 + 2]], 1);
}

__global__ void k_scan1(const int* __restrict__ deg, int* __restrict__ incl, int* __restrict__ bsum) {
    __shared__ int s[1024];
    int i = blockIdx.x * 1024 + threadIdx.x;
    int v = (i < NN) ? deg[i] : 0;
    s[threadIdx.x] = v;
    __syncthreads();
    for (int off = 1; off < 1024; off <<= 1) {
        int t = (threadIdx.x >= off) ? s[threadIdx.x - off] : 0;
        __syncthreads();
        s[threadIdx.x] += t;
        __syncthreads();
    }
    if (i < NN) incl[i] = s[threadIdx.x];
    if (threadIdx.x == 1023) bsum[blockIdx.x] = s[1023];
}

__global__ void k_scan2(const int* __restrict__ bsum, int* __restrict__ boff) {
    if (threadIdx.x == 0 && blockIdx.x == 0) {
        int acc = 0;
        for (int i = 0; i < 49; ++i) { boff[i] = acc; acc += bsum[i]; }
    }
}

__global__ void k_scan3(const int* __restrict__ incl, const int* __restrict__ deg,
                        const int* __restrict__ boff, int* __restrict__ row_start) {
    int i = blockIdx.x * 1024 + threadIdx.x;
    if (i < NN) row_start[i] = incl[i] - deg[i] + boff[blockIdx.x];
}

__global__ void k_fill(const int* __restrict__ et, const int* __restrict__ row_start,
                       int* __restrict__ cursor, int* __restrict__ perm) {
    int e = blockIdx.x * 256 + threadIdx.x;
    if (e >= EE) return;
    int src = et[e * 3 + 0];
    int rel = et[e * 3 + 1];
    int dst = et[e * 3 + 2];
    int pos = row_start[dst] + atomicAdd(&cursor[dst], 1);
    perm[pos] = src | (rel << 16);      // src < 65536, rel < 16
}

// ---------------- fragment-major weight prep ----------------
__global__ void k_prep(const float* __restrict__ iw,
                       const float* __restrict__ basis0, const float* __restrict__ rootw0,
                       const float* __restrict__ basis1, const float* __restrict__ rootw1,
                       __bf16* __restrict__ WtInF, __bf16* __restrict__ WtF0, __bf16* __restrict__ WtF1) {
    int t = blockIdx.x * 256 + threadIdx.x;
    if (t < 2048) {
        int lane = t & 63, grp = t >> 6;       // grp = nblk*4+kk
        int kk = grp & 3, nblk = grp >> 2;
        int col = nblk * 16 + (lane & 15);
        int k0 = kk * 32 + (lane >> 4) * 8;
        bf16x8 v;
        #pragma unroll
        for (int j = 0; j < 8; ++j) v[j] = (__bf16)iw[(size_t)(k0 + j) * 128 + col];
        *(bf16x8*)(WtInF + (size_t)t * 8) = v;
        return;
    }
    t -= 2048;
    const float* basis = basis0; const float* rootw = rootw0; __bf16* W = WtF0;
    if (t >= 10240) { t -= 10240; basis = basis1; rootw = rootw1; W = WtF1; }
    if (t >= 10240) return;
    int lane = t & 63, grp = t >> 6;           // grp = nblk*20+kk
    int kk = grp % 20, nblk = grp / 20;
    int col = nblk * 16 + (lane & 15);
    int k0 = kk * 32 + (lane >> 4) * 8;
    bf16x8 v;
    #pragma unroll
    for (int j = 0; j < 8; ++j) {
        int k = k0 + j;
        float f = (k < 512) ? basis[(size_t)(k >> 7) * 16384 + (size_t)(k & 127) * 128 + col]
                            : rootw[(size_t)(k - 512) * 128 + col];
        v[j] = (__bf16)f;
    }
    *(bf16x8*)(W + (size_t)t * 8) = v;
}

// ---------------- input GEMM: x0 = nf(f32) @ input_w + b (bf16 out), 64-row tiles ----------------
__global__ void k_gemm_in(const float* __restrict__ A, const __bf16* __restrict__ WtInF,
                          const float* __restrict__ bias, __bf16* __restrict__ out, int M) {
    const int tid = threadIdx.x, wave = tid >> 6, lane = tid & 63;
    const int wr = wave >> 1, wc = wave & 1;
    const int l15 = lane & 15, lhi = lane >> 4;
    f32x4 acc[2][4] = {};
    #define LDAI(dst, KK) do { \
        _Pragma("unroll") \
        for (int m = 0; m < 2; ++m) { \
            int rw = blockIdx.x * 64 + wr * 32 + m * 16 + l15; \
            rw = rw < M ? rw : M - 1; \
            const float* ap = A + (size_t)rw * 128 + (KK) * 32 + lhi * 8; \
            float4 v0 = *(const float4*)ap, v1 = *(const float4*)(ap + 4); \
            bf16x8 f; \
            f[0]=(__bf16)v0.x; f[1]=(__bf16)v0.y; f[2]=(__bf16)v0.z; f[3]=(__bf16)v0.w; \
            f[4]=(__bf16)v1.x; f[5]=(__bf16)v1.y; f[6]=(__bf16)v1.z; f[7]=(__bf16)v1.w; \
            dst[m] = f; \
        } } while (0)
    #define LDBI(dst, KK) do { \
        _Pragma("unroll") \
        for (int n = 0; n < 4; ++n) \
            dst[n] = *(const bf16x8*)(WtInF + (((size_t)(wc * 4 + n) * 4 + (KK)) * 64 + lane) * 8); \
        } while (0)
    #define MMI(AA, BB) do { \
        _Pragma("unroll") for (int m = 0; m < 2; ++m) \
        _Pragma("unroll") for (int n = 0; n < 4; ++n) \
            acc[m][n] = __builtin_amdgcn_mfma_f32_16x16x32_bf16(AA[m], BB[n], acc[m][n], 0, 0, 0); \
        } while (0)
    bf16x8 aP[2], bP[4], aQ[2], bQ[4];
    LDAI(aP, 0); LDBI(bP, 0);
    #pragma unroll
    for (int tstep = 0; tstep < 2; ++tstep) {
        LDAI(aQ, 2 * tstep + 1); LDBI(bQ, 2 * tstep + 1);
        MMI(aP, bP);
        if (tstep < 1) { LDAI(aP, 2 * tstep + 2); LDBI(bP, 2 * tstep + 2); }
        MMI(aQ, bQ);
    }
    #pragma unroll
    for (int m = 0; m < 2; ++m)
        #pragma unroll
        for (int j = 0; j < 4; ++j) {
            int row = blockIdx.x * 64 + wr * 32 + m * 16 + lhi * 4 + j;
            if (row >= M) continue;
            #pragma unroll
            for (int n = 0; n < 4; ++n) {
                int col = wc * 64 + n * 16 + l15;
                out[(size_t)row * 128 + col] = (__bf16)(acc[m][n][j] + bias[col]);
            }
        }
}

// ---------------- gather + aggregate: fp8 payload, agg4 schedule ----------------
// one wave per dst node; 16 lanes per edge (lane owns 8 channels, 8 B fp8);
// 8 edges per iteration, 2 loads in flight per lane.
__global__ void k_agg7(const unsigned char* __restrict__ x8, const int* __restrict__ perm,
                       const int* __restrict__ rowst, const int* __restrict__ deg,
                       const float* __restrict__ att, __bf16* __restrict__ aggF,
                       int nodeOff, int nodeCnt) {
    __shared__ float4 satt[16];
    if (threadIdx.x < 16) satt[threadIdx.x] = ((const float4*)att)[threadIdx.x];
    __syncthreads();
    int local = blockIdx.x * 4 + (threadIdx.x >> 6);
    if (local >= nodeCnt) return;
    int lane = threadIdx.x & 63;
    int e4 = lane >> 4, c8 = lane & 15;
    int node = nodeOff + local;
    int start = rowst[node], cnt = deg[node];
    float acc[4][8] = {};
    int nIt = (cnt + 3) >> 2;
    for (int it = 0; it < nIt; it += 2) {
        int eA = it * 4 + e4, eB = eA + 4;
        bool vA = eA < cnt, vB = eB < cnt;
        int pA = vA ? perm[start + eA] : 0;
        int pB = vB ? perm[start + eB] : 0;
        uint2 uA = *(const uint2*)(x8 + (size_t)(pA & 0xFFFF) * 128 + c8 * 8);
        uint2 uB = *(const uint2*)(x8 + (size_t)(pB & 0xFFFF) * 128 + c8 * 8);
        float4 cA = vA ? satt[pA >> 16] : make_float4(0.f, 0.f, 0.f, 0.f);
        float4 cB = vB ? satt[pB >> 16] : make_float4(0.f, 0.f, 0.f, 0.f);
        float fA[8], fB[8];
        fp8x8_to_f(uA, fA);
        fp8x8_to_f(uB, fB);
        #pragma unroll
        for (int j = 0; j < 8; ++j) {
            acc[0][j] += cA.x * fA[j]; acc[1][j] += cA.y * fA[j];
            acc[2][j] += cA.z * fA[j]; acc[3][j] += cA.w * fA[j];
        }
        #pragma unroll
        for (int j = 0; j < 8; ++j) {
            acc[0][j] += cB.x * fB[j]; acc[1][j] += cB.y * fB[j];
            acc[2][j] += cB.z * fB[j]; acc[3][j] += cB.w * fB[j];
        }
    }
    float dinv = (cnt > 0) ? 1.f / (float)cnt : 0.f;
    #pragma unroll
    for (int b = 0; b < 4; ++b)
        #pragma unroll
        for (int j = 0; j < 8; ++j) {
            float v = acc[b][j];
            v += __shfl_xor(v, 16);
            v += __shfl_xor(v, 32);
            acc[b][j] = v * dinv;
        }
    bf16x8 o;
    #pragma unroll
    for (int j = 0; j < 8; ++j) {
        float v = (e4 == 0) ? acc[0][j] : (e4 == 1) ? acc[1][j] : (e4 == 2) ? acc[2][j] : acc[3][j];
        o[j] = (__bf16)v;
    }
    size_t idx8 = (((size_t)(local >> 4) * 16 + e4 * 4 + (c8 >> 2)) * 64 + (c8 & 3) * 16 + (local & 15)) * 8;
    *(bf16x8*)(aggF + idx8) = o;
}

// ---------------- layer GEMM: y = [agg | x] @ W + rb ; LN(+ReLU) fused; 64-row tiles ----------------
template<int OUTF>
__global__ void k_gemm_layer(const __bf16* __restrict__ aggF, const __bf16* __restrict__ x,
                             const __bf16* __restrict__ WtF, const float* __restrict__ rb,
                             const float* __restrict__ g, const float* __restrict__ bb,
                             __bf16* __restrict__ outB, float* __restrict__ outF,
                             int rowOff, int nodeCnt) {
    __shared__ float red[2][2][64];
    __shared__ float murs[2][64];
    const int tid = threadIdx.x, wave = tid >> 6, lane = tid & 63;
    const int wr = wave >> 1, wc = wave & 1;
    const int l15 = lane & 15, lhi = lane >> 4;
    const int rowgrpBase = blockIdx.x * 4 + wr * 2;   // 16-node fragment groups
    f32x4 acc[2][4] = {};
    #define LDA(dst, KK) do { \
        _Pragma("unroll") \
        for (int m = 0; m < 2; ++m) { \
            if ((KK) < 16) { \
                dst[m] = *(const bf16x8*)(aggF + (((size_t)(rowgrpBase + m) * 16 + (KK)) * 64 + lane) * 8); \
            } else { \
                int rw = blockIdx.x * 64 + wr * 32 + m * 16 + l15; \
                rw = rw < nodeCnt ? rw : nodeCnt - 1; \
                dst[m] = *(const bf16x8*)(x + (size_t)(rowOff + rw) * 128 + ((KK) - 16) * 32 + lhi * 8); \
            } \
        } } while (0)
    #define LDB(dst, KK) do { \
        _Pragma("unroll") \
        for (int n = 0; n < 4; ++n) \
            dst[n] = *(const bf16x8*)(WtF + (((size_t)(wc * 4 + n) * 20 + (KK)) * 64 + lane) * 8); \
        } while (0)
    #define MM(AA, BB) do { \
        _Pragma("unroll") for (int m = 0; m < 2; ++m) \
        _Pragma("unroll") for (int n = 0; n < 4; ++n) \
            acc[m][n] = __builtin_amdgcn_mfma_f32_16x16x32_bf16(AA[m], BB[n], acc[m][n], 0, 0, 0); \
        } while (0)
    bf16x8 aP[2], bP[4], aQ[2], bQ[4];
    LDA(aP, 0); LDB(bP, 0);
    #pragma unroll
    for (int t = 0; t < 10; ++t) {
        LDA(aQ, 2 * t + 1); LDB(bQ, 2 * t + 1);
        MM(aP, bP);
        if (t < 9) { LDA(aP, 2 * t + 2); LDB(bP, 2 * t + 2); }
        MM(aQ, bQ);
    }
    float colb[4];
    #pragma unroll
    for (int n = 0; n < 4; ++n) colb[n] = rb[wc * 64 + n * 16 + l15];
    #pragma unroll
    for (int m = 0; m < 2; ++m)
        #pragma unroll
        for (int j = 0; j < 4; ++j) {
            float s = 0.f, q = 0.f;
            #pragma unroll
            for (int n = 0; n < 4; ++n) {
                float v = acc[m][n][j] + colb[n];
                acc[m][n][j] = v;
                s += v; q += v * v;
            }
            #pragma unroll
            for (int o = 1; o < 16; o <<= 1) { s += __shfl_xor(s, o); q += __shfl_xor(q, o); }
            if (l15 == 0) {
                int r = wr * 32 + m * 16 + lhi * 4 + j;
                red[0][wc][r] = s; red[1][wc][r] = q;
            }
        }
    __syncthreads();
    if (tid < 64) {
        float s = red[0][0][tid] + red[0][1][tid];
        float q = red[1][0][tid] + red[1][1][tid];
        float mu = s * (1.f / 128.f);
        float var = q * (1.f / 128.f) - mu * mu;
        murs[0][tid] = mu;
        murs[1][tid] = rsqrtf(var + 1e-5f);
    }
    __syncthreads();
    float gg[4], gb[4];
    #pragma unroll
    for (int n = 0; n < 4; ++n) {
        int col = wc * 64 + n * 16 + l15;
        gg[n] = g[col]; gb[n] = bb[col];
    }
    #pragma unroll
    for (int m = 0; m < 2; ++m)
        #pragma unroll
        for (int j = 0; j < 4; ++j) {
            int rblk = wr * 32 + m * 16 + lhi * 4 + j;
            int lr = blockIdx.x * 64 + rblk;
            if (lr >= nodeCnt) continue;
            float mu = murs[0][rblk], rs = murs[1][rblk];
            size_t rowbase = (size_t)(rowOff + lr) * 128;
            #pragma unroll
            for (int n = 0; n < 4; ++n) {
                int col = wc * 64 + n * 16 + l15;
                float v = (acc[m][n][j] - mu) * rs * gg[n] + gb[n];
                if (OUTF == 0) { v = fmaxf(v, 0.f); outB[rowbase + col] = (__bf16)v; }
                else           { outF[rowbase + col] = v; }
            }
        }
}

// ---------------- launch ----------------
extern "C" void kernel_launch(void* const* d_in, const int* in_sizes, int n_in,
                              void* d_out, int out_size, void* d_ws, size_t ws_size,
                              hipStream_t stream) {
    const float* nf      = (const float*)d_in[0];
    const int*   et      = (const int*)d_in[1];
    const float* input_w = (const float*)d_in[3];
    const float* input_b = (const float*)d_in[4];
    const float* basis0  = (const float*)d_in[5];
    const float* att0    = (const float*)d_in[6];
    const float* rootw0  = (const float*)d_in[7];
    const float* rootb0  = (const float*)d_in[8];
    const float* lng0    = (const float*)d_in[9];
    const float* lnb0    = (const float*)d_in[10];
    const float* basis1  = (const float*)d_in[11];
    const float* att1    = (const float*)d_in[12];
    const float* rootw1  = (const float*)d_in[13];
    const float* rootb1  = (const float*)d_in[14];
    const float* lng1    = (const float*)d_in[15];
    const float* lnb1    = (const float*)d_in[16];
    (void)in_sizes; (void)n_in; (void)out_size;

    char* ws = (char*)d_ws;
    size_t off = 0;
    auto carve = [&](size_t bytes) { char* p = ws + off; off = (off + bytes + 255) & ~(size_t)255; return p; };
    __bf16* x0    = (__bf16*)carve((size_t)NN * 128 * 2);
    __bf16* x1    = (__bf16*)carve((size_t)NN * 128 * 2);
    unsigned char* x08 = (unsigned char*)carve((size_t)NN * 128);
    unsigned char* x18 = (unsigned char*)carve((size_t)NN * 128);
    __bf16* WtInF = (__bf16*)carve((size_t)128 * 128 * 2);
    __bf16* WtF0  = (__bf16*)carve((size_t)128 * 640 * 2);
    __bf16* WtF1  = (__bf16*)carve((size_t)128 * 640 * 2);
    int*    deg   = (int*)carve((size_t)NN * 4);
    int*    incl  = (int*)carve((size_t)NN * 4);
    int*    rowst = (int*)carve((size_t)NN * 4);
    int*    curs  = (int*)carve((size_t)NN * 4);
    int*    bsum  = (int*)carve(64 * 4);
    int*    boff  = (int*)carve(64 * 4);
    int*    perm  = (int*)carve((size_t)EE * 4 + 64);
    size_t remain = (ws_size > off + 4096) ? (ws_size - off - 4096) : 0;
    long long maxNodes = (long long)(remain / 1024);
    int chunkN = (maxNodes >= NN) ? NN : (int)maxNodes;
    if (chunkN < 512) chunkN = 512;
    chunkN = (chunkN + 63) & ~63;
    __bf16* aggF = (__bf16*)carve((size_t)chunkN * 512 * 2);
    int nch = (NN + chunkN - 1) / chunkN;

    // CSR build
    k_zero<<<NBLK, 256, 0, stream>>>(deg, curs);
    k_deg<<<(EE + 255) / 256, 256, 0, stream>>>(et, deg);
    k_scan1<<<49, 1024, 0, stream>>>(deg, incl, bsum);
    k_scan2<<<1, 64, 0, stream>>>(bsum, boff);
    k_scan3<<<49, 1024, 0, stream>>>(incl, deg, boff, rowst);
    k_fill<<<(EE + 255) / 256, 256, 0, stream>>>(et, rowst, curs, perm);

    // weights + input projection
    k_prep<<<88, 256, 0, stream>>>(input_w, basis0, rootw0, basis1, rootw1, WtInF, WtF0, WtF1);
    k_gemm_in<<<(NN + 63) / 64, 256, 0, stream>>>(nf, WtInF, input_b, x0, NN);
    k_cvt8<<<(NN * 16 + 255) / 256, 256, 0, stream>>>(x0, x08, NN * 16);

    // layer 0
    for (int c = 0; c < nch; ++c) {
        int o0 = c * chunkN;
        int cnt = (o0 + chunkN <= NN) ? chunkN : (NN - o0);
        k_agg7<<<(cnt + 3) / 4, 256, 0, stream>>>(x08, perm, rowst, deg, att0, aggF, o0, cnt);
        k_gemm_layer<0><<<(cnt + 63) / 64, 256, 0, stream>>>(aggF, x0, WtF0, rootb0, lng0, lnb0,
                                                             x1, nullptr, o0, cnt);
    }
    k_cvt8<<<(NN * 16 + 255) / 256, 256, 0, stream>>>(x1, x18, NN * 16);

    // layer 1
    for (int c = 0; c < nch; ++c) {
        int o0 = c * chunkN;
        int cnt = (o0 + chunkN <= NN) ? chunkN : (NN - o0);
        k_agg7<<<(cnt + 3) / 4, 256, 0, stream>>>(x18, perm, rowst, deg, att1, aggF, o0, cnt);
        k_gemm_layer<1><<<(cnt + 63) / 64, 256, 0, stream>>>(aggF, x1, WtF1, rootb1, lng1, lnb1,
                                                             nullptr, (float*)d_out, o0, cnt);
    }
}